// Round 1
// baseline (127.070 us; speedup 1.0000x reference)
//
#include <hip/hip_runtime.h>
#include <math.h>

// Problem constants (match reference)
#define BGRAPH 64
#define N_PER  1024
#define KSEL   512
#define NTOT   65536       // BGRAPH * N_PER
#define EDG    2097152
#define FIN    256
#define FE     16

// d_out flat layout (float32 elements), reference tuple order:
//   x_out   [32768,256]  @ 0          (8388608)
//   ei_new  [2,E]        @ 8388608    (4194304)
//   ea_new  [E,16]       @ 12582912   (33554432)
//   batch   [32768]      @ 46137344
//   perm    [32768]      @ 46170112
//   score   [65536]      @ 46202880
//   emask   [E]          @ 46268416
#define OFF_XOUT   0
#define OFF_EI     8388608
#define OFF_EA     12582912
#define OFF_BATCH  46137344
#define OFF_PERM   46170112
#define OFF_SCORE  46202880
#define OFF_EMASK  46268416

// ---------------------------------------------------------------------------
// Kernel 1: score[n] = tanh(dot(x[n], W) + b). One wave (64 lanes) per node,
// float4 per lane (perfectly coalesced 1 KB/row). f64 accumulate + f64 tanh
// to track the checker's numpy-f64 ordering as closely as possible.
__global__ __launch_bounds__(256) void score_kernel(
    const float* __restrict__ x, const float* __restrict__ W,
    const float* __restrict__ bptr, float* __restrict__ score_out) {
  int wave = threadIdx.x >> 6;
  int lane = threadIdx.x & 63;
  int node = blockIdx.x * 4 + wave;
  const float4* xr = reinterpret_cast<const float4*>(x + (size_t)node * FIN);
  const float4* wr = reinterpret_cast<const float4*>(W);
  float4 xv = xr[lane];
  float4 wv = wr[lane];
  double p = (double)xv.x * (double)wv.x + (double)xv.y * (double)wv.y +
             (double)xv.z * (double)wv.z + (double)xv.w * (double)wv.w;
#pragma unroll
  for (int off = 32; off >= 1; off >>= 1) p += __shfl_xor(p, off, 64);
  if (lane == 0) {
    double s = tanh(p + (double)bptr[0]);
    score_out[node] = (float)s;   // MULTIPLIER == 1.0
  }
}

// ---------------------------------------------------------------------------
// Kernel 2: per-graph bitonic sort of 1024 (score, idx) pairs in LDS.
// Final order: descending score, ties -> ascending index (lax.top_k stable).
// Writes perm/batch outputs (as f32) and node_map (-1 = dropped) into d_ws.
__global__ __launch_bounds__(1024) void topk_kernel(
    const float* __restrict__ score, float* __restrict__ perm_out,
    float* __restrict__ batch_out, int* __restrict__ node_map) {
  __shared__ float sk[N_PER];
  __shared__ int   si[N_PER];
  int b = blockIdx.x;
  int t = threadIdx.x;
  int base = b * N_PER;
  sk[t] = score[base + t];
  si[t] = t;
  node_map[base + t] = -1;   // this block owns exactly its graph's slice
  __syncthreads();
  for (int k = 2; k <= N_PER; k <<= 1) {
    for (int j = k >> 1; j > 0; j >>= 1) {
      int ixj = t ^ j;
      if (ixj > t) {
        float a = sk[t], c = sk[ixj];
        int ia = si[t], ic = si[ixj];
        // "t precedes ixj" in final order:
        bool prec = (a > c) || (a == c && ia < ic);
        bool dirUp = ((t & k) == 0);
        bool doswap = dirUp ? !prec : prec;
        if (doswap) { sk[t] = c; sk[ixj] = a; si[t] = ic; si[ixj] = ia; }
      }
      __syncthreads();
    }
  }
  if (t < KSEL) {
    int g   = base + si[t];         // global node id
    int gid = b * KSEL + t;         // new (remapped) id
    perm_out[gid]  = (float)g;
    batch_out[gid] = (float)b;
    node_map[g]    = gid;
  }
}

// ---------------------------------------------------------------------------
// Kernel 3: x_out[r] = x[perm[r]] * score[perm[r]]. One wave per row.
__global__ __launch_bounds__(256) void gather_kernel(
    const float* __restrict__ x, const float* __restrict__ perm_f,
    const float* __restrict__ score, float* __restrict__ xout) {
  int wave = threadIdx.x >> 6;
  int lane = threadIdx.x & 63;
  int r = blockIdx.x * 4 + wave;
  int g = (int)perm_f[r];           // exact (<= 65535)
  float s = score[g];
  float4 v = reinterpret_cast<const float4*>(x + (size_t)g * FIN)[lane];
  float4 o;
  o.x = v.x * s; o.y = v.y * s; o.z = v.z * s; o.w = v.w * s;
  reinterpret_cast<float4*>(xout + (size_t)r * FIN)[lane] = o;
}

// ---------------------------------------------------------------------------
// Kernel 4: edge mask + id remap. Thread per edge; node_map gathers hit the
// 256 KB L2-resident ws array.
__global__ __launch_bounds__(256) void edgeA_kernel(
    const int* __restrict__ ei, const int* __restrict__ node_map,
    float* __restrict__ ei_out, float* __restrict__ emask_out) {
  int e = blockIdx.x * 256 + threadIdx.x;
  int r = ei[e];
  int c = ei[EDG + e];
  int nr = node_map[r];
  int nc = node_map[c];
  bool m = (nr >= 0) && (nc >= 0);
  ei_out[e]       = m ? (float)nr : -1.0f;
  ei_out[EDG + e] = m ? (float)nc : -1.0f;
  emask_out[e]    = m ? 1.0f : 0.0f;
}

// ---------------------------------------------------------------------------
// Kernel 5: ea_new = edge_mask ? edge_attr : 0. 4 threads/edge (float4 each,
// perfectly coalesced); edge_attr read predicated on mask (~75% read saved).
__global__ __launch_bounds__(256) void edgeB_kernel(
    const float* __restrict__ ea, const float* __restrict__ emask,
    float* __restrict__ ea_out) {
  int t = blockIdx.x * 256 + threadIdx.x;   // t = e*4 + q
  float m = emask[t >> 2];
  float4 v = make_float4(0.f, 0.f, 0.f, 0.f);
  if (m != 0.0f) v = reinterpret_cast<const float4*>(ea)[t];
  reinterpret_cast<float4*>(ea_out)[t] = v;
}

// ---------------------------------------------------------------------------
extern "C" void kernel_launch(void* const* d_in, const int* in_sizes, int n_in,
                              void* d_out, int out_size, void* d_ws, size_t ws_size,
                              hipStream_t stream) {
  const float* x  = (const float*)d_in[0];
  const int*   ei = (const int*)d_in[1];
  const float* ea = (const float*)d_in[2];
  // d_in[3] = batch (unused: graphs are contiguous & equal size)
  const float* W  = (const float*)d_in[4];
  const float* bb = (const float*)d_in[5];

  float* out       = (float*)d_out;
  float* xout      = out + OFF_XOUT;
  float* ei_out    = out + OFF_EI;
  float* ea_out    = out + OFF_EA;
  float* batch_out = out + OFF_BATCH;
  float* perm_out  = out + OFF_PERM;
  float* score_out = out + OFF_SCORE;
  float* emask_out = out + OFF_EMASK;

  int* node_map = (int*)d_ws;   // NTOT ints = 256 KB

  score_kernel <<<NTOT / 4, 256, 0, stream>>>(x, W, bb, score_out);
  topk_kernel  <<<BGRAPH, 1024, 0, stream>>>(score_out, perm_out, batch_out, node_map);
  gather_kernel<<<(BGRAPH * KSEL) / 4, 256, 0, stream>>>(x, perm_out, score_out, xout);
  edgeA_kernel <<<EDG / 256, 256, 0, stream>>>(ei, node_map, ei_out, emask_out);
  edgeB_kernel <<<(EDG * 4) / 256, 256, 0, stream>>>(ea, emask_out, ea_out);
}

// Round 2
// 117.781 us; speedup vs baseline: 1.0789x; 1.0789x over previous
//
#include <hip/hip_runtime.h>
#include <math.h>

// Problem constants (match reference)
#define BGRAPH 64
#define N_PER  1024
#define KSEL   512
#define NTOT   65536       // BGRAPH * N_PER
#define EDG    2097152
#define FIN    256
#define FE     16

// d_out flat layout (float32 elements), reference tuple order:
#define OFF_XOUT   0
#define OFF_EI     8388608
#define OFF_EA     12582912
#define OFF_BATCH  46137344
#define OFF_PERM   46170112
#define OFF_SCORE  46202880
#define OFF_EMASK  46268416

// ---------------------------------------------------------------------------
// Kernel 1: score[n] = tanh(dot(x[n], W) + b). One wave per node, float4/lane
// (coalesced 1 KB/row). f64 accumulate + f64 tanh: rank order at the K
// boundary must match the numpy-f64 reference exactly (a membership flip
// would put ~32k-scale errors in ei_new, far over threshold).
__global__ __launch_bounds__(256) void score_kernel(
    const float* __restrict__ x, const float* __restrict__ W,
    const float* __restrict__ bptr, float* __restrict__ score_out) {
  int wave = threadIdx.x >> 6;
  int lane = threadIdx.x & 63;
  int node = blockIdx.x * 4 + wave;
  const float4* xr = reinterpret_cast<const float4*>(x + (size_t)node * FIN);
  const float4* wr = reinterpret_cast<const float4*>(W);
  float4 xv = xr[lane];
  float4 wv = wr[lane];
  double p = (double)xv.x * (double)wv.x + (double)xv.y * (double)wv.y +
             (double)xv.z * (double)wv.z + (double)xv.w * (double)wv.w;
#pragma unroll
  for (int off = 32; off >= 1; off >>= 1) p += __shfl_xor(p, off, 64);
  if (lane == 0) {
    double s = tanh(p + (double)bptr[0]);
    score_out[node] = (float)s;   // MULTIPLIER == 1.0
  }
}

// ---------------------------------------------------------------------------
// Kernel 2: per-graph bitonic sort of 1024 (score, idx) pairs.
// Hybrid: element lives in registers; j<=32 phases exchange via __shfl_xor
// (no barrier), j>=64 phases via LDS (2 barriers). 20 barriers vs 55.
// Final order: descending score, ties ascending index (lax.top_k stable).
__global__ __launch_bounds__(1024) void topk_kernel(
    const float* __restrict__ score, float* __restrict__ perm_out,
    float* __restrict__ batch_out, int* __restrict__ node_map) {
  __shared__ float sk[N_PER];
  __shared__ int   si[N_PER];
  int b = blockIdx.x;
  int t = threadIdx.x;
  int base = b * N_PER;
  float key = score[base + t];
  int   idx = t;
  node_map[base + t] = -1;   // block owns exactly its graph's slice
  for (int k = 2; k <= N_PER; k <<= 1) {
    for (int j = k >> 1; j > 0; j >>= 1) {
      bool lower = (t & j) == 0;
      bool dirUp = (t & k) == 0;
      float okey; int oidx;
      if (j >= 64) {
        sk[t] = key; si[t] = idx;
        __syncthreads();
        okey = sk[t ^ j]; oidx = si[t ^ j];
        __syncthreads();
      } else {
        okey = __shfl_xor(key, j, 64);
        oidx = __shfl_xor(idx, j, 64);
      }
      // own element precedes partner's in final (desc, idx-asc) order?
      bool own_prec = (key > okey) || (key == okey && idx < oidx);
      bool want_prec = (lower == dirUp);
      if (own_prec != want_prec) { key = okey; idx = oidx; }
    }
  }
  if (t < KSEL) {
    int g   = base + idx;          // global node id
    int gid = b * KSEL + t;        // remapped id (rank order)
    perm_out[gid]  = (float)g;
    batch_out[gid] = (float)b;
    node_map[g]    = gid;
  }
}

// ---------------------------------------------------------------------------
// Kernel 3: x_out[r] = x[perm[r]] * score[perm[r]]. One wave per row.
__global__ __launch_bounds__(256) void gather_kernel(
    const float* __restrict__ x, const float* __restrict__ perm_f,
    const float* __restrict__ score, float* __restrict__ xout) {
  int wave = threadIdx.x >> 6;
  int lane = threadIdx.x & 63;
  int r = blockIdx.x * 4 + wave;
  int g = (int)perm_f[r];           // exact (<= 65535)
  float s = score[g];
  float4 v = reinterpret_cast<const float4*>(x + (size_t)g * FIN)[lane];
  float4 o;
  o.x = v.x * s; o.y = v.y * s; o.z = v.z * s; o.w = v.w * s;
  reinterpret_cast<float4*>(xout + (size_t)r * FIN)[lane] = o;
}

// ---------------------------------------------------------------------------
// Kernel 4 (fused edgeA+edgeB): block handles 64 edges.
// Lanes 0..63: mask + remap + ei/emask writes, mask stashed in LDS.
// All 256 threads: float4 ea copy (read predicated on mask, write always —
// output buffer is poisoned so zeros must be written).
__global__ __launch_bounds__(256) void edge_kernel(
    const int* __restrict__ ei, const int* __restrict__ node_map,
    const float* __restrict__ ea, float* __restrict__ ei_out,
    float* __restrict__ emask_out, float* __restrict__ ea_out) {
  __shared__ float smask[64];
  int base = blockIdx.x * 64;
  int tid = threadIdx.x;
  if (tid < 64) {
    int e = base + tid;
    int r = ei[e];
    int c = ei[EDG + e];
    int nr = node_map[r];
    int nc = node_map[c];
    bool m = (nr >= 0) && (nc >= 0);
    ei_out[e]       = m ? (float)nr : -1.0f;
    ei_out[EDG + e] = m ? (float)nc : -1.0f;
    float mf = m ? 1.0f : 0.0f;
    emask_out[e] = mf;
    smask[tid]   = mf;
  }
  __syncthreads();
  int q = base * 4 + tid;           // float4 index into ea (4 per edge)
  float m = smask[tid >> 2];
  float4 v = make_float4(0.f, 0.f, 0.f, 0.f);
  if (m != 0.0f) v = reinterpret_cast<const float4*>(ea)[q];
  reinterpret_cast<float4*>(ea_out)[q] = v;
}

// ---------------------------------------------------------------------------
extern "C" void kernel_launch(void* const* d_in, const int* in_sizes, int n_in,
                              void* d_out, int out_size, void* d_ws, size_t ws_size,
                              hipStream_t stream) {
  const float* x  = (const float*)d_in[0];
  const int*   ei = (const int*)d_in[1];
  const float* ea = (const float*)d_in[2];
  // d_in[3] = batch (unused: graphs contiguous & equal size)
  const float* W  = (const float*)d_in[4];
  const float* bb = (const float*)d_in[5];

  float* out       = (float*)d_out;
  float* xout      = out + OFF_XOUT;
  float* ei_out    = out + OFF_EI;
  float* ea_out    = out + OFF_EA;
  float* batch_out = out + OFF_BATCH;
  float* perm_out  = out + OFF_PERM;
  float* score_out = out + OFF_SCORE;
  float* emask_out = out + OFF_EMASK;

  int* node_map = (int*)d_ws;   // NTOT ints = 256 KB

  score_kernel <<<NTOT / 4, 256, 0, stream>>>(x, W, bb, score_out);
  topk_kernel  <<<BGRAPH, 1024, 0, stream>>>(score_out, perm_out, batch_out, node_map);
  gather_kernel<<<(BGRAPH * KSEL) / 4, 256, 0, stream>>>(x, perm_out, score_out, xout);
  edge_kernel  <<<EDG / 64, 256, 0, stream>>>(ei, node_map, ea, ei_out, emask_out, ea_out);
}

// Round 4
// 117.515 us; speedup vs baseline: 1.0813x; 1.0023x over previous
//
#include <hip/hip_runtime.h>
#include <math.h>

// Problem constants (match reference)
#define BGRAPH 64
#define N_PER  1024
#define KSEL   512
#define NTOT   65536       // BGRAPH * N_PER
#define EDG    2097152
#define FIN    256
#define FE     16

// Native clang vector type: __builtin_nontemporal_* requires a true vector
// type, not HIP's float4 struct (R3 compile failure).
typedef float v4f __attribute__((ext_vector_type(4)));

// d_out flat layout (float32 elements), reference tuple order:
#define OFF_XOUT   0
#define OFF_EI     8388608
#define OFF_EA     12582912
#define OFF_BATCH  46137344
#define OFF_PERM   46170112
#define OFF_SCORE  46202880
#define OFF_EMASK  46268416

// ---------------------------------------------------------------------------
// Kernel 1: score[n] = tanh(dot(x[n], W) + b). One wave per node, float4/lane
// (coalesced 1 KB/row). f64 accumulate + f64 tanh: rank order at the K
// boundary must match the numpy-f64 reference exactly (a membership flip
// would put ~32k-scale errors in ei_new, far over threshold). PASSED twice
// with absmax 128 << 1310 threshold — do not touch this path.
// x loads stay NORMAL (x is re-read by gather; we want it L3-resident).
__global__ __launch_bounds__(256) void score_kernel(
    const float* __restrict__ x, const float* __restrict__ W,
    const float* __restrict__ bptr, float* __restrict__ score_out) {
  int wave = threadIdx.x >> 6;
  int lane = threadIdx.x & 63;
  int node = blockIdx.x * 4 + wave;
  const float4* xr = reinterpret_cast<const float4*>(x + (size_t)node * FIN);
  const float4* wr = reinterpret_cast<const float4*>(W);
  float4 xv = xr[lane];
  float4 wv = wr[lane];
  double p = (double)xv.x * (double)wv.x + (double)xv.y * (double)wv.y +
             (double)xv.z * (double)wv.z + (double)xv.w * (double)wv.w;
#pragma unroll
  for (int off = 32; off >= 1; off >>= 1) p += __shfl_xor(p, off, 64);
  if (lane == 0) {
    double s = tanh(p + (double)bptr[0]);
    score_out[node] = (float)s;   // MULTIPLIER == 1.0
  }
}

// ---------------------------------------------------------------------------
// Kernel 2: per-graph bitonic sort of 1024 (score, idx) pairs.
// Hybrid: element lives in registers; j<=32 phases exchange via __shfl_xor
// (no barrier), j>=64 phases via LDS (2 barriers). 20 barriers vs 55.
// Final order: descending score, ties ascending index (lax.top_k stable).
__global__ __launch_bounds__(1024) void topk_kernel(
    const float* __restrict__ score, float* __restrict__ perm_out,
    float* __restrict__ batch_out, int* __restrict__ node_map) {
  __shared__ float sk[N_PER];
  __shared__ int   si[N_PER];
  int b = blockIdx.x;
  int t = threadIdx.x;
  int base = b * N_PER;
  float key = score[base + t];
  int   idx = t;
  node_map[base + t] = -1;   // block owns exactly its graph's slice
  for (int k = 2; k <= N_PER; k <<= 1) {
    for (int j = k >> 1; j > 0; j >>= 1) {
      bool lower = (t & j) == 0;
      bool dirUp = (t & k) == 0;
      float okey; int oidx;
      if (j >= 64) {
        sk[t] = key; si[t] = idx;
        __syncthreads();
        okey = sk[t ^ j]; oidx = si[t ^ j];
        __syncthreads();
      } else {
        okey = __shfl_xor(key, j, 64);
        oidx = __shfl_xor(idx, j, 64);
      }
      // own element precedes partner's in final (desc, idx-asc) order?
      bool own_prec = (key > okey) || (key == okey && idx < oidx);
      bool want_prec = (lower == dirUp);
      if (own_prec != want_prec) { key = okey; idx = oidx; }
    }
  }
  if (t < KSEL) {
    int g   = base + idx;          // global node id
    int gid = b * KSEL + t;        // remapped id (rank order)
    perm_out[gid]  = (float)g;
    __builtin_nontemporal_store((float)b, batch_out + gid);
    node_map[g]    = gid;
  }
}

// ---------------------------------------------------------------------------
// Kernel 3: x_out[r] = x[perm[r]] * score[perm[r]]. One wave per row.
// x read is its LAST use -> nontemporal load (still hits L3 if resident,
// won't re-allocate). Output write-once -> nontemporal store.
__global__ __launch_bounds__(256) void gather_kernel(
    const float* __restrict__ x, const float* __restrict__ perm_f,
    const float* __restrict__ score, float* __restrict__ xout) {
  int wave = threadIdx.x >> 6;
  int lane = threadIdx.x & 63;
  int r = blockIdx.x * 4 + wave;
  int g = (int)perm_f[r];           // exact (<= 65535)
  float s = score[g];
  const v4f* xr = reinterpret_cast<const v4f*>(x + (size_t)g * FIN);
  v4f v = __builtin_nontemporal_load(xr + lane);
  v4f o = v * s;
  __builtin_nontemporal_store(o, reinterpret_cast<v4f*>(xout + (size_t)r * FIN) + lane);
}

// ---------------------------------------------------------------------------
// Kernel 4 (fused edge mask + remap + attr copy): 256 edges per block.
// Phase 1: thread-per-edge (full 256-thread utilization, 1 KB coalesced ei
//          reads), mask stashed in LDS, ei/emask written nontemporal.
// Phase 2: 4 coalesced float4 passes over edge_attr; read predicated on mask
//          (~75% of the 128 MB read skipped), write always (poisoned buffer).
// LDS mask reads: 4-lane same-address broadcast + 2-way alias = conflict-free.
__global__ __launch_bounds__(256) void edge_kernel(
    const int* __restrict__ ei, const int* __restrict__ node_map,
    const float* __restrict__ ea, float* __restrict__ ei_out,
    float* __restrict__ emask_out, float* __restrict__ ea_out) {
  __shared__ float smask[256];
  int t = threadIdx.x;
  int e0 = blockIdx.x * 256;
  int e = e0 + t;
  int r = __builtin_nontemporal_load(ei + e);
  int c = __builtin_nontemporal_load(ei + EDG + e);
  int nr = node_map[r];
  int nc = node_map[c];
  bool m = (nr >= 0) && (nc >= 0);
  __builtin_nontemporal_store(m ? (float)nr : -1.0f, ei_out + e);
  __builtin_nontemporal_store(m ? (float)nc : -1.0f, ei_out + EDG + e);
  float mf = m ? 1.0f : 0.0f;
  __builtin_nontemporal_store(mf, emask_out + e);
  smask[t] = mf;
  __syncthreads();
  const v4f* ea4 = reinterpret_cast<const v4f*>(ea) + (size_t)e0 * 4;
  v4f*      out4 = reinterpret_cast<v4f*>(ea_out)   + (size_t)e0 * 4;
#pragma unroll
  for (int q = 0; q < 4; ++q) {
    int fi = q * 256 + t;                 // local float4 index in [0,1024)
    float mm = smask[fi >> 2];
    v4f v = (v4f)(0.0f);
    if (mm != 0.0f) v = __builtin_nontemporal_load(ea4 + fi);
    __builtin_nontemporal_store(v, out4 + fi);
  }
}

// ---------------------------------------------------------------------------
extern "C" void kernel_launch(void* const* d_in, const int* in_sizes, int n_in,
                              void* d_out, int out_size, void* d_ws, size_t ws_size,
                              hipStream_t stream) {
  const float* x  = (const float*)d_in[0];
  const int*   ei = (const int*)d_in[1];
  const float* ea = (const float*)d_in[2];
  // d_in[3] = batch (unused: graphs contiguous & equal size)
  const float* W  = (const float*)d_in[4];
  const float* bb = (const float*)d_in[5];

  float* out       = (float*)d_out;
  float* xout      = out + OFF_XOUT;
  float* ei_out    = out + OFF_EI;
  float* ea_out    = out + OFF_EA;
  float* batch_out = out + OFF_BATCH;
  float* perm_out  = out + OFF_PERM;
  float* score_out = out + OFF_SCORE;
  float* emask_out = out + OFF_EMASK;

  int* node_map = (int*)d_ws;   // NTOT ints = 256 KB

  score_kernel <<<NTOT / 4, 256, 0, stream>>>(x, W, bb, score_out);
  topk_kernel  <<<BGRAPH, 1024, 0, stream>>>(score_out, perm_out, batch_out, node_map);
  gather_kernel<<<(BGRAPH * KSEL) / 4, 256, 0, stream>>>(x, perm_out, score_out, xout);
  edge_kernel  <<<EDG / 256, 256, 0, stream>>>(ei, node_map, ea, ei_out, emask_out, ea_out);
}